// Round 6
// baseline (363.933 us; speedup 1.0000x reference)
//
#include <hip/hip_runtime.h>
#include <stdint.h>

// ===========================================================================
// SESSION LEDGER (do not retry without new information):
//  r0  prep_fused + 128x128 splitK=4 GEMM                    -> 356.5us TOTAL
//      (GEMM 311us, 886 TF, MfmaUtil 42%, VALUBusy 51%, occ 39%). REPRODUCED.
//  r7  256^2 8-wave 4-phase lockstep, A built in P4           -> 445 (GEMM 425)
//  r8  same + dbuf A/B, derived waits                         -> 427 (GEMM 409)
//  r9  r3 + dbuf B + counted vmcnt + sched_barrier in main    -> 457 (GEMM 447;
//      m141 mode: VGPR 64->112, occ collapse)
//  r10 256^2 pure-DMA lockstep (y materialized)               -> 515 (GEMM 388;
//      VALU 11%, conflicts 0, Mfma 30% -> lockstep barrier gaps; also its
//      ph3/4-issued loads had only ~700cyc cover < HBM ~900cyc)
//  r11 (this): producer-consumer wave specialization — the documented
//      "path past 36%" (AITER approach). Consumers = r3 inner loop verbatim,
//      1 barrier/iter, zero vmem/asm. Producers carry DMA depth-2 (3-buf B),
//      A-build depth-1 (2-buf A), counted vmcnt(5)+lgkm(0) isolated in the
//      register-light branch. 80KB LDS -> 2 blocks/CU. setprio now has real
//      role-split (T5 prerequisite, m218b).
//  Falsifier (pre-committed): GEMM >= 311us => revert r0, declare plateau.
// ===========================================================================

#define NB   4096
#define DIN  1024
#define DOUT 1024
#define NL   32
#define KPW  (DIN * NL)     // 32768
#define KTOT (KPW + 64)     // 32832 (pad: 32 bias cols + 32 zero cols)
#define BKT  64
#define NSPLIT 4            // split-K ways: 129+128+128+128

typedef __attribute__((ext_vector_type(8))) short short8;          // 8 bf16
typedef __attribute__((ext_vector_type(8))) unsigned short ushort8;
typedef __attribute__((ext_vector_type(4))) float floatx4;         // C/D frag

// float -> bf16 bits, round-to-nearest-even (finite inputs only)
__device__ __forceinline__ unsigned short f2bf(float v) {
    uint32_t u = __float_as_uint(v);
    return (unsigned short)((u + 0x7FFFu + ((u >> 16) & 1u)) >> 16);
}

// two floats -> packed bf16x2 (RNE), low half = a (proven numerics; r4's
// cheaper trunc pack regressed -> keep RNE)
__device__ __forceinline__ uint32_t f2bf2(float a, float b) {
    uint32_t ua = __float_as_uint(a), ub = __float_as_uint(b);
    ua += 0x7FFFu + ((ua >> 16) & 1u);
    ub += 0x7FFFu + ((ub >> 16) & 1u);
    return __builtin_amdgcn_perm(ub, ua, 0x07060302u);  // {ub_hi16, ua_hi16}
}

// async global->LDS, 16B per lane; LDS dst = wave-uniform base + lane*16
__device__ __forceinline__ void async_ld16(const void* g, void* l) {
    __builtin_amdgcn_global_load_lds(
        (const __attribute__((address_space(1))) void*)g,
        (__attribute__((address_space(3))) void*)l, 16, 0, 0);
}

// ---------------------------------------------------------------------------
// Fused prep (unchanged r6 config; ~44us, near its ~37us HBM roofline):
//   blocks [0,1024)    : pw fp32 (+pb) -> bf16 pwb row
//   blocks [1024,2048) : gating softmax, 4 rows/block -> g fp32
//   blocks [2048,2112) : zero d_out (harness poisons it 0xAA each replay)
// ---------------------------------------------------------------------------
__global__ __launch_bounds__(256) void prep_fused(
    const float* __restrict__ x, const float* __restrict__ gw,
    const float* __restrict__ gb, const float* __restrict__ pw,
    const float* __restrict__ pb, float* __restrict__ g,
    unsigned short* __restrict__ pwb, float* __restrict__ C)
{
    const int id = blockIdx.x;
    const int t  = threadIdx.x;

    if (id < DOUT) {
        const int o = id;
        const float* src = pw + (size_t)o * KPW;
        unsigned short* dst = pwb + (size_t)o * KTOT;
        #pragma unroll 2
        for (int s = 0; s < 16; ++s) {
            const int k = (s * 256 + t) * 8;
            const float4 a = *(const float4*)(src + k);
            const float4 c = *(const float4*)(src + k + 4);
            ushort8 o8;
            o8[0] = f2bf(a.x); o8[1] = f2bf(a.y); o8[2] = f2bf(a.z); o8[3] = f2bf(a.w);
            o8[4] = f2bf(c.x); o8[5] = f2bf(c.y); o8[6] = f2bf(c.z); o8[7] = f2bf(c.w);
            *(ushort8*)(dst + k) = o8;
        }
        if (t < 8) {   // tail: 32 bias cols + 32 zeros
            ushort8 o8;
            #pragma unroll
            for (int j = 0; j < 8; ++j) {
                const int l = t * 8 + j;
                o8[j] = (l < NL) ? f2bf(pb[(size_t)o * NL + l]) : (unsigned short)0;
            }
            *(ushort8*)(dst + KPW + t * 8) = o8;
        }
    } else if (id < DOUT + NB / 4) {
        const int wave = t >> 6;
        const int lane = t & 63;
        const int b = (id - DOUT) * 4 + wave;
        const int l = lane & 31;
        const int c = lane >> 5;
        const float* xrow = x + (size_t)b * DIN;
        float p0 = 0.f, p1 = 0.f, p2 = 0.f, p3 = 0.f;
        const int i0 = c * 512;
        #pragma unroll 2
        for (int j = 0; j < 512; j += 4) {
            const int i = i0 + j;
            p0 = fmaf(xrow[i + 0], gw[(i + 0) * NL + l], p0);
            p1 = fmaf(xrow[i + 1], gw[(i + 1) * NL + l], p1);
            p2 = fmaf(xrow[i + 2], gw[(i + 2) * NL + l], p2);
            p3 = fmaf(xrow[i + 3], gw[(i + 3) * NL + l], p3);
        }
        float p = (p0 + p1) + (p2 + p3);
        p += __shfl_xor(p, 32);
        const float logit = p + gb[l];
        float m = logit;
        for (int off = 16; off > 0; off >>= 1) m = fmaxf(m, __shfl_xor(m, off));
        const float e = __expf(logit - m);
        float s = e;
        for (int off = 16; off > 0; off >>= 1) s += __shfl_xor(s, off);
        if (lane < NL) g[(size_t)b * NL + l] = e / s;
    } else {
        const int zb = id - (DOUT + NB / 4);
        float4* dst = (float4*)C + (size_t)zb * (256 * 64) + t;
        const float4 z4 = {0.f, 0.f, 0.f, 0.f};
        #pragma unroll 4
        for (int s = 0; s < 64; ++s) dst[s * 256] = z4;
    }
}

// ---------------------------------------------------------------------------
// gemm_pc: producer-consumer wave specialization over the r3 tile scheme.
// 512 threads: waves 0-3 CONSUMERS (own r3's 64x64 quadrants, acc, epilogue;
// per iter: 1 __syncthreads + 16 ds_read_b128 + 32 MFMA; NO vmem, NO asm).
// Waves 4-7 PRODUCERS: per iter, after the barrier: load x(j+2), DMA B(j+2)
// into Bs[(j+2)%3] (depth-2: ~2 iters of latency cover), build A(j+1) into
// As[(j+1)&1] (r3's exact build, depth-1), then counted
// s_waitcnt vmcnt(5) lgkmcnt(0) -- never a full drain; the fragile asm lives
// only in this register-light branch (avoids r9's m141 regalloc collapse).
// Slot safety: read slots (j&1, j%3) disjoint from write slots ((j+1)&1,
// (j+2)%3); consumer reads drain inside their __syncthreads before the
// producer's next-iter overwrite; last-iter A-build skipped (race avoidance).
// LDS 2*16 + 3*16 = 80KB -> 2 blocks/CU (16 waves/CU); grid 512 blocks of
// 512 thr = exactly resident. setprio(1) around MFMA: real role-split/SIMD.
// ---------------------------------------------------------------------------
__global__ __launch_bounds__(512, 4) void gemm_pc(
    const float* __restrict__ X,            // x [NB][DIN] fp32
    const float* __restrict__ G,            // g [NB][NL]  fp32
    const unsigned short* __restrict__ Bw,  // pwb [DOUT][KTOT] bf16
    float* __restrict__ C)                  // [NB][DOUT], pre-zeroed
{
    __shared__ __align__(16) unsigned short As[2][128 * BKT];  // 32 KB
    __shared__ __align__(16) unsigned short Bs[3][128 * BKT];  // 48 KB

    const int t    = threadIdx.x;
    const int wave = t >> 6;

    // grid decode identical to r3: 8 bn-blocks sharing one (bm,z) per XCD
    const int id  = blockIdx.x;
    const int xcd = id & 7;
    const int s_  = id >> 3;               // 0..63
    const int bn  = (s_ & 7) * 128;
    const int idx = xcd * 8 + (s_ >> 3);   // 0..63
    const int bm  = ((idx & 31)) * 128;
    const int z   = idx >> 5;              // 0..1  -- wait: need 0..3
    // NOTE: with 512 blocks total: s_ in 0..63, idx in 0..63 gives 32 bm x 2 z.
    // Recompute properly below.
    (void)z;
    const int idx2 = xcd * 16 + (s_ >> 3); // 0..127 (s_>>3 in 0..7)
    const int bm2  = (idx2 & 31) * 128;
    const int z2   = idx2 >> 5;            // 0..3
    const int bmF  = bm2; (void)bm;
    const int it0  = z2 * 128 + (z2 ? 1 : 0);  // splits: 129+128+128+128
    const int it1  = (z2 + 1) * 128 + 1;
    const int nt   = it1 - it0;

    if (wave < 4) {
        // ================= CONSUMERS (r3 inner loop verbatim) =============
        const int lane = t & 63;
        const int wm   = (wave >> 1) * 64;
        const int wn   = (wave & 1) * 64;
        const int ml   = lane & 15;
        const int quad = lane >> 4;
        const int xorm = ml & 7;

        floatx4 acc[4][4] = {};

        int sB = 0;   // j % 3
        for (int j = 0; j < nt; ++j) {
            __syncthreads();   // buf j published (A built+drained, B landed)
            const unsigned short* aT = &As[j & 1][0];
            const unsigned short* bT = &Bs[sB][0];
            __builtin_amdgcn_s_setprio(1);
            #pragma unroll
            for (int kk = 0; kk < 2; ++kk) {
                const int swz = ((kk * 4 + quad) ^ xorm) * 8;
                short8 af[4], bf[4];
                #pragma unroll
                for (int im = 0; im < 4; ++im)
                    af[im] = *(const short8*)(aT + (wm + im * 16 + ml) * BKT + swz);
                #pragma unroll
                for (int in = 0; in < 4; ++in)
                    bf[in] = *(const short8*)(bT + (wn + in * 16 + ml) * BKT + swz);
                #pragma unroll
                for (int im = 0; im < 4; ++im)
                    #pragma unroll
                    for (int in = 0; in < 4; ++in)
                        acc[im][in] = __builtin_amdgcn_mfma_f32_16x16x32_bf16(
                            af[im], bf[in], acc[im][in], 0, 0, 0);
            }
            __builtin_amdgcn_s_setprio(0);
            sB = (sB == 2) ? 0 : sB + 1;
        }

        // epilogue: C/D map col=lane&15, row=quad*4+reg (m89-verified)
        #pragma unroll
        for (int im = 0; im < 4; ++im)
            #pragma unroll
            for (int in = 0; in < 4; ++in) {
                const int row = bmF + wm + im * 16 + quad * 4;
                const int col = bn + wn + in * 16 + ml;
                #pragma unroll
                for (int rr = 0; rr < 4; ++rr)
                    atomicAdd(&C[(size_t)(row + rr) * DOUT + col], acc[im][in][rr]);
            }
    } else {
        // ================= PRODUCERS ======================================
        const int pt = t - 256;            // 0..255
        const int pw_ = wave - 4;          // 0..3

        // B staging (r2-proven pre-swizzled source), by producer threads
        const int row0 = pt >> 3;          // 0..31
        const int uc   = (((pt & 7) ^ ((pt >> 3) & 7)) * 8);
        const unsigned short* Bg = Bw + (size_t)(bn + row0) * KTOT + uc;
        const int lofs = pw_ * 512;        // elems; HW adds lane*16B

        // A build (r3-proven): thread owns row r, leaves lh
        const int r   = pt >> 1;           // 0..127
        const int lh  = (pt & 1) * 16;
        const int rx  = r & 7;
        const float* xp = X + (size_t)(bmF + r) * DIN;

        float gq[16];
        {
            const float* gp = G + (size_t)(bmF + r) * NL + lh;
            #pragma unroll
            for (int q = 0; q < 4; ++q) {
                const float4 v = *(const float4*)(gp + q * 4);
                gq[q * 4 + 0] = v.x; gq[q * 4 + 1] = v.y;
                gq[q * 4 + 2] = v.z; gq[q * 4 + 3] = v.w;
            }
        }

        // ---- prologue: x(it0), x(it0+1); DMA B(it0)->Bs0, B(it0+1)->Bs1;
        //      build A(it0)->As0; vmcnt(4) (B(it0+1) stays in flight) ----
        float2 x0     = *(const float2*)(xp + min(it0 * 2, DIN - 2));
        float2 xv_cur = *(const float2*)(xp + min((it0 + 1) * 2, DIN - 2));
        {
            const unsigned short* s0 = Bg + (size_t)it0 * BKT;
            #pragma unroll
            for (int s = 0; s < 4; ++s)
                async_ld16(s0 + (size_t)(s * 32) * KTOT, &Bs[0][lofs + s * 2048]);
            const unsigned short* s1 = s0 + BKT;
            #pragma unroll
            for (int s = 0; s < 4; ++s)
                async_ld16(s1 + (size_t)(s * 32) * KTOT, &Bs[1][lofs + s * 2048]);
        }
        {
            const bool inb = (it0 * 2) < DIN;
            const float xa = inb ? x0.x : 1.0f;
            const float xb = inb ? x0.y : 0.0f;
            unsigned short* Aw = &As[0][r * BKT];
            #pragma unroll
            for (int ii = 0; ii < 2; ++ii) {
                const float xs = ii ? xb : xa;
                #pragma unroll
                for (int jj = 0; jj < 2; ++jj) {
                    uint4 v;
                    v.x = f2bf2(xs * gq[jj * 8 + 0], xs * gq[jj * 8 + 1]);
                    v.y = f2bf2(xs * gq[jj * 8 + 2], xs * gq[jj * 8 + 3]);
                    v.z = f2bf2(xs * gq[jj * 8 + 4], xs * gq[jj * 8 + 5]);
                    v.w = f2bf2(xs * gq[jj * 8 + 6], xs * gq[jj * 8 + 7]);
                    const int c = ii * 4 + (pt & 1) * 2 + jj;
                    *(uint4*)(Aw + ((c ^ rx) * 8)) = v;
                }
            }
        }
        asm volatile("s_waitcnt vmcnt(4) lgkmcnt(0)" ::: "memory");

        int sB2 = 2;   // (j+2) % 3 at j=0
        for (int j = 0; j < nt; ++j) {
            __builtin_amdgcn_s_barrier();   // pairs with consumers' syncthreads

            // 1) x(it0+j+2) first (so its future use auto-waits vmcnt(5), not 0)
            float2 xv_next = *(const float2*)(xp + min((it0 + j + 2) * 2, DIN - 2));

            // 2) DMA B(j+2) -> Bs[(j+2)%3] (clamped dummy re-stage at tail)
            {
                const int tf = it0 + ((j + 2 < nt) ? (j + 2) : (nt - 1));
                const unsigned short* sf = Bg + (size_t)tf * BKT;
                unsigned short* db = &Bs[sB2][lofs];
                #pragma unroll
                for (int s = 0; s < 4; ++s)
                    async_ld16(sf + (size_t)(s * 32) * KTOT, db + s * 2048);
            }

            // 3) build A(j+1) -> As[(j+1)&1]  (skip at tail: race avoidance)
            if (j + 1 < nt) {
                const int T = it0 + j + 1;
                const bool inb = (T * 2) < DIN;
                const float xa = inb ? xv_cur.x : 1.0f;  // i=1024: y-col = g
                const float xb = inb ? xv_cur.y : 0.0f;  // i=1025: zero pad
                unsigned short* Aw = &As[(j + 1) & 1][r * BKT];
                #pragma unroll
                for (int ii = 0; ii < 2; ++ii) {
                    const float xs = ii ? xb : xa;
                    #pragma unroll
                    for (int jj = 0; jj < 2; ++jj) {
                        uint4 v;
                        v.x = f2bf2(xs * gq[jj * 8 + 0], xs * gq[jj * 8 + 1]);
                        v.y = f2bf2(xs * gq[jj * 8 + 2], xs * gq[jj * 8 + 3]);
                        v.z = f2bf2(xs * gq[jj * 8 + 4], xs * gq[jj * 8 + 5]);
                        v.w = f2bf2(xs * gq[jj * 8 + 6], xs * gq[jj * 8 + 7]);
                        const int c = ii * 4 + (pt & 1) * 2 + jj;
                        *(uint4*)(Aw + ((c ^ rx) * 8)) = v;
                    }
                }
            }
            xv_cur = xv_next;

            // 4) counted drain: B(j+1) + own A-writes done; this iter's
            //    {x, 4 DMA(j+2)} = 5 newest stay in flight. Never vmcnt(0).
            asm volatile("s_waitcnt vmcnt(5) lgkmcnt(0)" ::: "memory");

            sB2 = (sB2 == 2) ? 0 : sB2 + 1;
        }
        // producers exit; no barriers after the loop on either path
    }
}

// ---------------------------------------------------------------------------
extern "C" void kernel_launch(void* const* d_in, const int* in_sizes, int n_in,
                              void* d_out, int out_size, void* d_ws, size_t ws_size,
                              hipStream_t stream) {
    const float* x  = (const float*)d_in[0];   // [4096,1024]
    const float* gw = (const float*)d_in[1];   // [1024,32]
    const float* gb = (const float*)d_in[2];   // [32]
    const float* pw = (const float*)d_in[3];   // [1024,1024,32]
    const float* pb = (const float*)d_in[4];   // [1024,32]
    float* out = (float*)d_out;                // [4096,1024]

    float* g            = (float*)d_ws;                               // 512 KB
    unsigned short* pwb = (unsigned short*)((char*)d_ws + (1 << 20)); // 67.2 MB

    prep_fused<<<DOUT + NB / 4 + 64, 256, 0, stream>>>(x, gw, gb, pw, pb, g, pwb, out);
    gemm_pc<<<(DOUT / 128) * (NB / 128) * NSPLIT, 512, 0, stream>>>(x, g, pwb, out);
}

// Round 7
// 356.205 us; speedup vs baseline: 1.0217x; 1.0217x over previous
//
#include <hip/hip_runtime.h>
#include <stdint.h>

// ===========================================================================
// SESSION LEDGER — FINAL (6 structural arcs; do not retry without new info):
//  r0  prep_fused + 128x128 splitK=4 GEMM          -> 356.4us TOTAL [BEST, x2]
//      (GEMM 311us, 886 TF, MfmaUtil 42%, VALUBusy 51%, occ 39%).
//  r7  256^2 8-wave 4-phase lockstep, A in P4      -> 445 (GEMM 425)
//  r8  + dbuf A/B, derived waits, 2-deep x pipe    -> 427 (GEMM 409)
//  r9  r3 + dbuf B + vmcnt + sched_barrier in main -> 457 (GEMM 447; m141 mode)
//  r10 256^2 pure-DMA lockstep (y materialized)    -> 515 (GEMM 388; VALU 11%,
//      conflicts 0, Mfma 30% -> lockstep barrier gaps are structural)
//  r11 producer-consumer wave specialization       -> 364 (GEMM 323; Mfma 39%,
//      VGPR 52, FETCH +58% from prefetch reuse-distance; dedicated producer
//      waves = lost MFMA issue slots. Closest alternative; still < r3.)
//  CONCLUSION: r3's undifferentiated-TLP structure (12 mixed waves/CU,
//  compiler-scheduled) beats every explicit overlap expressible here —
//  consistent with m114 (implicit wave overlap) + m97 plateau + m232
//  (8-phase does not reproduce from scratch in plain HIP). 275.5 GFLOP is
//  algebraically minimal; fp8/MX risks absmax. This kernel is final.
// ===========================================================================

#define NB   4096
#define DIN  1024
#define DOUT 1024
#define NL   32
#define KPW  (DIN * NL)     // 32768
#define KTOT (KPW + 64)     // 32832 (pad: 32 bias cols + 32 zero cols)
#define BKT  64
#define KITERS (KTOT / BKT) // 513
#define NSPLIT 4            // split-K ways: 129+128+128+128 (r3 best: 311us)

typedef __attribute__((ext_vector_type(8))) short short8;          // 8 bf16 (A/B frag)
typedef __attribute__((ext_vector_type(8))) unsigned short ushort8;
typedef __attribute__((ext_vector_type(4))) float floatx4;         // C/D frag

// float -> bf16 bits, round-to-nearest-even (finite inputs only)
__device__ __forceinline__ unsigned short f2bf(float v) {
    uint32_t u = __float_as_uint(v);
    return (unsigned short)((u + 0x7FFFu + ((u >> 16) & 1u)) >> 16);
}

// two floats -> packed bf16x2 (RNE), low half = a (r3 config; r4's trunc pack
// regressed 311->326: A-build VALU is NOT on the critical path)
__device__ __forceinline__ uint32_t f2bf2(float a, float b) {
    uint32_t ua = __float_as_uint(a), ub = __float_as_uint(b);
    ua += 0x7FFFu + ((ua >> 16) & 1u);
    ub += 0x7FFFu + ((ub >> 16) & 1u);
    return __builtin_amdgcn_perm(ub, ua, 0x07060302u);  // {ub_hi16, ua_hi16}
}

// async global->LDS, 16B per lane; LDS dst = wave-uniform base + lane*16
__device__ __forceinline__ void async_ld16(const void* g, void* l) {
    __builtin_amdgcn_global_load_lds(
        (const __attribute__((address_space(1))) void*)g,
        (__attribute__((address_space(3))) void*)l, 16, 0, 0);
}

// ---------------------------------------------------------------------------
// Fused prep (ONE dispatch replaces memset + gate + build_pwb; r6):
//   blocks [0,1024)    : pw fp32 (+pb) -> bf16 pwb row
//   blocks [1024,2048) : gating softmax, 4 rows/block -> g fp32
//   blocks [2048,2112) : zero d_out (harness poisons it 0xAA each replay)
// Role branch is block-uniform. GEMM depends on all three via stream order.
// ---------------------------------------------------------------------------
__global__ __launch_bounds__(256) void prep_fused(
    const float* __restrict__ x, const float* __restrict__ gw,
    const float* __restrict__ gb, const float* __restrict__ pw,
    const float* __restrict__ pb, float* __restrict__ g,
    unsigned short* __restrict__ pwb, float* __restrict__ C)
{
    const int id = blockIdx.x;
    const int t  = threadIdx.x;

    if (id < DOUT) {
        // ---- role 1: pwb build (HBM-bound: 134MB read + 67MB write) ----
        const int o = id;
        const float* src = pw + (size_t)o * KPW;
        unsigned short* dst = pwb + (size_t)o * KTOT;
        #pragma unroll 2
        for (int s = 0; s < 16; ++s) {
            const int k = (s * 256 + t) * 8;
            const float4 a = *(const float4*)(src + k);
            const float4 c = *(const float4*)(src + k + 4);
            ushort8 o8;
            o8[0] = f2bf(a.x); o8[1] = f2bf(a.y); o8[2] = f2bf(a.z); o8[3] = f2bf(a.w);
            o8[4] = f2bf(c.x); o8[5] = f2bf(c.y); o8[6] = f2bf(c.z); o8[7] = f2bf(c.w);
            *(ushort8*)(dst + k) = o8;
        }
        if (t < 8) {   // tail: 32 bias cols + 32 zeros
            ushort8 o8;
            #pragma unroll
            for (int j = 0; j < 8; ++j) {
                const int l = t * 8 + j;
                o8[j] = (l < NL) ? f2bf(pb[(size_t)o * NL + l]) : (unsigned short)0;
            }
            *(ushort8*)(dst + KPW + t * 8) = o8;
        }
    } else if (id < DOUT + NB / 4) {
        // ---- role 2: gating softmax, one wave per row ----
        const int wave = t >> 6;
        const int lane = t & 63;
        const int b = (id - DOUT) * 4 + wave;
        const int l = lane & 31;
        const int c = lane >> 5;
        const float* xrow = x + (size_t)b * DIN;
        float p0 = 0.f, p1 = 0.f, p2 = 0.f, p3 = 0.f;
        const int i0 = c * 512;
        #pragma unroll 2
        for (int j = 0; j < 512; j += 4) {
            const int i = i0 + j;
            p0 = fmaf(xrow[i + 0], gw[(i + 0) * NL + l], p0);
            p1 = fmaf(xrow[i + 1], gw[(i + 1) * NL + l], p1);
            p2 = fmaf(xrow[i + 2], gw[(i + 2) * NL + l], p2);
            p3 = fmaf(xrow[i + 3], gw[(i + 3) * NL + l], p3);
        }
        float p = (p0 + p1) + (p2 + p3);
        p += __shfl_xor(p, 32);
        const float logit = p + gb[l];
        float m = logit;
        for (int off = 16; off > 0; off >>= 1) m = fmaxf(m, __shfl_xor(m, off));
        const float e = __expf(logit - m);
        float s = e;
        for (int off = 16; off > 0; off >>= 1) s += __shfl_xor(s, off);
        if (lane < NL) g[(size_t)b * NL + l] = e / s;
    } else {
        // ---- role 3: zero C (16MB / 64 blocks = 64 float4-iters/thread) ----
        const int zb = id - (DOUT + NB / 4);
        float4* dst = (float4*)C + (size_t)zb * (256 * 64) + t;
        const float4 z4 = {0.f, 0.f, 0.f, 0.f};
        #pragma unroll 4
        for (int s = 0; s < 64; ++s) dst[s * 256] = z4;
    }
}

// ---------------------------------------------------------------------------
// GEMM (exact r3 config — best measured: 311us, 886 TF, at the documented
// m97-structure plateau): C[b,o] += sum_k y[b,k]*pwb[o,k], y built on the fly
// in LDS (y[b,i*32+l] = bf16(x[b,i]*g[b,l]); bias iter i=1024 uses x==1).
// 128x128 tile, BK=64, split-K=4, XOR-swizzled LDS (r2: conflicts 1e8->0).
// Register budget: 64 VGPR + 64 AGPR = 128 -> 4 waves/SIMD -> 4 blocks/CU
// hard cap (r5 lesson: grid/split-K can't raise occupancy past this).
// DO NOT: add asm waits/sched_barriers (r9), double-buffer (r9), move to
// 256^2 phases (r7/r8/r10), or split producer/consumer waves (r11) — all
// measured worse; see ledger at top.
// ---------------------------------------------------------------------------
__global__ __launch_bounds__(256, 4) void gemm_splitk(
    const float* __restrict__ X,            // x [NB][DIN] fp32
    const float* __restrict__ G,            // g [NB][NL]  fp32
    const unsigned short* __restrict__ Bw,  // pwb [DOUT][KTOT] bf16
    float* __restrict__ C)                  // [NB][DOUT], pre-zeroed
{
    __shared__ unsigned short As[128 * BKT];
    __shared__ unsigned short Bs[128 * BKT];

    const int t    = threadIdx.x;
    const int wave = t >> 6;
    const int lane = t & 63;

    // XCD-aware decode: 8 bn-blocks sharing one (bm,z) A-panel -> same XCD L2
    const int id  = blockIdx.x;
    const int xcd = id & 7;
    const int s_  = id >> 3;               // 0..127
    const int bn  = (s_ & 7) * 128;
    const int idx = xcd * 16 + (s_ >> 3);  // 0..127
    const int bm  = (idx & 31) * 128;
    const int z   = idx >> 5;              // 0..3
    const int it0 = z * 128 + (z ? 1 : 0); // splits: 129+128+128+128
    const int it1 = (z + 1) * 128 + 1;

    const int wm = (wave >> 1) * 64;
    const int wn = (wave & 1) * 64;
    const int ml   = lane & 15;
    const int quad = lane >> 4;
    const int xorm = ml & 7;

    // B staging via async DMA (swizzled source, as r2)
    const int row0 = t >> 3;
    const int uc   = (((t & 7) ^ ((t >> 3) & 7)) * 8);
    const unsigned short* Bg = Bw + (size_t)(bn + row0) * KTOT + uc + (size_t)it0 * BKT;
    unsigned short* Bl = Bs + wave * 512;   // + s*2048 per chunk; HW adds lane*16B

    // A on-the-fly build: thread t owns row r=t>>1, leaves lh=(t&1)*16..+15
    const int r   = t >> 1;                 // row 0..127
    const int lh  = (t & 1) * 16;           // leaf base 0 or 16
    const int rx  = r & 7;
    const float* xp = X + (size_t)(bm + r) * DIN;
    unsigned short* Aw = As + r * BKT;
    float gq[16];
    {
        const float* gp = G + (size_t)(bm + r) * NL + lh;
        #pragma unroll
        for (int q = 0; q < 4; ++q) {
            const float4 v = *(const float4*)(gp + q * 4);
            gq[q * 4 + 0] = v.x; gq[q * 4 + 1] = v.y;
            gq[q * 4 + 2] = v.z; gq[q * 4 + 3] = v.w;
        }
    }

    floatx4 acc[4][4] = {};
    float2 xv = *(const float2*)(xp + min(it0 * 2, DIN - 2));

    for (int it = it0; it < it1; ++it) {
        // 1) B tile DMA (overlaps the VALU A-build below)
        #pragma unroll
        for (int s = 0; s < 4; ++s)
            async_ld16(Bg + (size_t)(s * 32) * KTOT, Bl + s * 2048);
        Bg += BKT;

        // 2) bias fixup (uniform branch; only it==512 hits it)
        const bool inb = (it * 2) < DIN;
        const float xa = inb ? xv.x : 1.0f;   // i=1024: y-col = g (pairs with pb)
        const float xb = inb ? xv.y : 0.0f;   // i=1025: zero pad
        // 3) prefetch next x (clamped; drained by the same pre-barrier wait)
        xv = *(const float2*)(xp + min((it + 1) * 2, DIN - 2));

        // 4) build 32 bf16 of As: rows fixed, chunks c = ii*4 + (t&1)*2 + j
        #pragma unroll
        for (int ii = 0; ii < 2; ++ii) {
            const float xs = ii ? xb : xa;
            #pragma unroll
            for (int j = 0; j < 2; ++j) {
                uint4 v;
                v.x = f2bf2(xs * gq[j * 8 + 0], xs * gq[j * 8 + 1]);
                v.y = f2bf2(xs * gq[j * 8 + 2], xs * gq[j * 8 + 3]);
                v.z = f2bf2(xs * gq[j * 8 + 4], xs * gq[j * 8 + 5]);
                v.w = f2bf2(xs * gq[j * 8 + 6], xs * gq[j * 8 + 7]);
                const int c = ii * 4 + (t & 1) * 2 + j;
                *(uint4*)(Aw + ((c ^ rx) * 8)) = v;
            }
        }
        __syncthreads();

        #pragma unroll
        for (int kk = 0; kk < 2; ++kk) {
            const int swz = ((kk * 4 + quad) ^ xorm) * 8;
            short8 af[4], bf[4];
            #pragma unroll
            for (int im = 0; im < 4; ++im)
                af[im] = *(const short8*)(As + (wm + im * 16 + ml) * BKT + swz);
            #pragma unroll
            for (int in = 0; in < 4; ++in)
                bf[in] = *(const short8*)(Bs + (wn + in * 16 + ml) * BKT + swz);
            #pragma unroll
            for (int im = 0; im < 4; ++im)
                #pragma unroll
                for (int in = 0; in < 4; ++in)
                    acc[im][in] = __builtin_amdgcn_mfma_f32_16x16x32_bf16(
                        af[im], bf[in], acc[im][in], 0, 0, 0);
        }
        __syncthreads();
    }

    // epilogue: C/D map col=lane&15, row=quad*4+reg (m89-verified); atomic for split-K
    #pragma unroll
    for (int im = 0; im < 4; ++im)
        #pragma unroll
        for (int in = 0; in < 4; ++in) {
            const int row = bm + wm + im * 16 + quad * 4;
            const int col = bn + wn + in * 16 + ml;
            #pragma unroll
            for (int rr = 0; rr < 4; ++rr)
                atomicAdd(&C[(size_t)(row + rr) * DOUT + col], acc[im][in][rr]);
        }
}

// ---------------------------------------------------------------------------
extern "C" void kernel_launch(void* const* d_in, const int* in_sizes, int n_in,
                              void* d_out, int out_size, void* d_ws, size_t ws_size,
                              hipStream_t stream) {
    const float* x  = (const float*)d_in[0];   // [4096,1024]
    const float* gw = (const float*)d_in[1];   // [1024,32]
    const float* gb = (const float*)d_in[2];   // [32]
    const float* pw = (const float*)d_in[3];   // [1024,1024,32]
    const float* pb = (const float*)d_in[4];   // [1024,32]
    float* out = (float*)d_out;                // [4096,1024]

    float* g            = (float*)d_ws;                               // 512 KB
    unsigned short* pwb = (unsigned short*)((char*)d_ws + (1 << 20)); // 67.2 MB
    // ws use: 1 MB + 1024*32832*2 = ~68.3 MB

    // One fused prep dispatch: pwb (1024 blocks) + gate (1024) + zero-C (64)
    prep_fused<<<DOUT + NB / 4 + 64, 256, 0, stream>>>(x, gw, gb, pw, pb, g, pwb, out);
    gemm_splitk<<<(DOUT / 128) * (NB / 128) * NSPLIT, 256, 0, stream>>>(x, g, pwb, out);
}